// Round 3
// baseline (580.263 us; speedup 1.0000x reference)
//
#include <hip/hip_runtime.h>
#include <math.h>

#define D 256
#define B 16
#define L 8
#define N 128

static constexpr float LAMBDA_ASYNC = 0.08f;
static constexpr float LAMBDA_TAU   = 0.12f;

// ws layout (floats):
//   X_t[D*16]           @ 0        (transposed X: [d][b])
//   acc_t[8][D*16]      @ 4096     (transposed layer sums: [e][b])
//   fired[8][N]         @ 36864
//   total 37888 floats
#define WS_XT(ws)       (ws)
#define WS_ACCT(ws, l)  ((ws) + 4096 + (size_t)(l) * 4096)
#define WS_FIRED(ws, l) ((ws) + 36864 + (size_t)(l) * N)
#define WS_TOTAL        37888

__global__ __launch_bounds__(512) void zero_kernel(float* __restrict__ ws) {
    const int i = blockIdx.x * 512 + threadIdx.x;
    if (i < WS_TOTAL) ws[i] = 0.0f;
}

// X[b][d] -> X_t[d][b]
__global__ __launch_bounds__(256) void transpose_kernel(
    const float* __restrict__ X, float* __restrict__ ws) {
    const int d = threadIdx.x;
    float* xt = WS_XT(ws);
    #pragma unroll
    for (int b = 0; b < B; ++b) xt[d * B + b] = X[b * D + d];
}

// Grid: 512 blocks = node*4 + e-quarter. Block: 512 threads = 8 waves.
// Wave w handles d in [w*32, w*32+32); lane = e offset within the 64-e quarter.
__global__ __launch_bounds__(512, 4) void layer_kernel(
    const float* __restrict__ W,      // L*N*D*D
    const float* __restrict__ bias,   // L*N*D
    const float* __restrict__ S,      // L*N*D
    const float* __restrict__ rho,    // L*N
    const float* __restrict__ boost,  // L*N
    const int*  __restrict__ tb,
    float* __restrict__ ws,
    int l)
{
    __shared__ float red[8 * 64 * 17];   // [wave][e_local][b] padded, 34.8 KB
    __shared__ float sh[8];

    const int t    = threadIdx.x;
    const int w    = t >> 6;
    const int lane = t & 63;
    const int n    = blockIdx.x >> 2;
    const int e0   = (blockIdx.x & 3) * 64;

    const float* vt = (l == 0) ? WS_XT(ws) : WS_ACCT(ws, l - 1);  // [d][b]
    float* acct_cur = WS_ACCT(ws, l);

    // ---- preamble: rawdot = sum_d S[n,d] * (sum_b vt[d][b]);  cnt_prev
    float part = 0.0f, cnt_part = 0.0f;
    if (t < 256) {
        const int d = t;
        const float4 a0 = *(const float4*)&vt[d * B + 0];
        const float4 a1 = *(const float4*)&vt[d * B + 4];
        const float4 a2 = *(const float4*)&vt[d * B + 8];
        const float4 a3 = *(const float4*)&vt[d * B + 12];
        const float cs = a0.x + a0.y + a0.z + a0.w + a1.x + a1.y + a1.z + a1.w
                       + a2.x + a2.y + a2.z + a2.w + a3.x + a3.y + a3.z + a3.w;
        part = cs * S[(size_t)(l * N + n) * D + d];
    }
    if (w == 4 && l > 0) {
        const float* fp = WS_FIRED(ws, l - 1);
        cnt_part = fp[lane] + fp[lane + 64];
    }
    #pragma unroll
    for (int o = 32; o > 0; o >>= 1) {
        part     += __shfl_down(part, o);
        cnt_part += __shfl_down(cnt_part, o);
    }
    if (lane == 0) sh[w] = (w < 4) ? part : cnt_part;
    __syncthreads();

    float scale;
    bool has_input;
    if (l == 0) { scale = 1.0f; has_input = true; }
    else {
        const float cnt_raw = sh[4];
        has_input = (cnt_raw > 0.0f);
        scale = expf(-LAMBDA_ASYNC) / fmaxf(cnt_raw, 1.0f);
    }
    {
        const float rawdot = sh[0] + sh[1] + sh[2] + sh[3];
        const float sdot = scale * rawdot * (1.0f / 16.0f);
        const float tau  = 0.5f * expf(LAMBDA_TAU * ((float)(l + 1) - (float)tb[0]));
        const bool fired = (rho[l * N + n] + sdot + boost[l * N + n] >= tau) && has_input;
        if (blockIdx.x == (unsigned)(n << 2) && t == 0)
            WS_FIRED(ws, l)[n] = fired ? 1.0f : 0.0f;
        if (!fired) return;   // block-uniform
    }

    // ---- main loop: no LDS, no shuffles. W coalesced rows; vt broadcast via L1.
    const float* wcol = W + ((size_t)(l * N + n) * D + (size_t)(w * 32)) * D + (e0 + lane);
    const float* vrow = vt + (size_t)(w * 32) * B;

    float acc[16];
    #pragma unroll
    for (int b = 0; b < 16; ++b) acc[b] = 0.0f;

    #pragma unroll 4
    for (int j = 0; j < 32; ++j) {
        const float wv = wcol[(size_t)j * D];
        const float4 v0 = *(const float4*)(vrow + j * B + 0);
        const float4 v1 = *(const float4*)(vrow + j * B + 4);
        const float4 v2 = *(const float4*)(vrow + j * B + 8);
        const float4 v3 = *(const float4*)(vrow + j * B + 12);
        acc[ 0] = fmaf(wv, v0.x, acc[ 0]);
        acc[ 1] = fmaf(wv, v0.y, acc[ 1]);
        acc[ 2] = fmaf(wv, v0.z, acc[ 2]);
        acc[ 3] = fmaf(wv, v0.w, acc[ 3]);
        acc[ 4] = fmaf(wv, v1.x, acc[ 4]);
        acc[ 5] = fmaf(wv, v1.y, acc[ 5]);
        acc[ 6] = fmaf(wv, v1.z, acc[ 6]);
        acc[ 7] = fmaf(wv, v1.w, acc[ 7]);
        acc[ 8] = fmaf(wv, v2.x, acc[ 8]);
        acc[ 9] = fmaf(wv, v2.y, acc[ 9]);
        acc[10] = fmaf(wv, v2.z, acc[10]);
        acc[11] = fmaf(wv, v2.w, acc[11]);
        acc[12] = fmaf(wv, v3.x, acc[12]);
        acc[13] = fmaf(wv, v3.y, acc[13]);
        acc[14] = fmaf(wv, v3.z, acc[14]);
        acc[15] = fmaf(wv, v3.w, acc[15]);
    }

    // ---- cross-wave d-reduce via padded LDS (stride 17: conflict-free scalar)
    {
        float* rr = &red[(w * 64 + lane) * 17];
        #pragma unroll
        for (int b = 0; b < 16; ++b) rr[b] = acc[b];
    }
    __syncthreads();

    // ---- epilogue: thread = (e2 = t&63, bp = t>>6 -> 2 b's); scale, bias, tanh
    {
        const int e2 = t & 63;
        const int bp = t >> 6;
        const float bv = bias[(size_t)(l * N + n) * D + e0 + e2];
        #pragma unroll
        for (int q = 0; q < 2; ++q) {
            const int b = bp * 2 + q;
            float s = 0.0f;
            #pragma unroll
            for (int w2 = 0; w2 < 8; ++w2)
                s += red[(w2 * 64 + e2) * 17 + b];
            const float val = tanhf(fmaf(scale, s, bv));
            atomicAdd(&acct_cur[(size_t)(e0 + e2) * B + b], val);
        }
    }
}

// out[b][e] = acc_t7[e][b] / max(cnt7, 1)
__global__ __launch_bounds__(256) void finalize_kernel(
    const float* __restrict__ ws, float* __restrict__ out)
{
    __shared__ float sh[2];
    const int t = threadIdx.x;
    const float* fired7 = ws + 36864 + (size_t)7 * N;
    float f = (t < N) ? fired7[t] : 0.0f;
    #pragma unroll
    for (int o = 32; o > 0; o >>= 1) f += __shfl_down(f, o);
    if ((t & 63) == 0) sh[t >> 6] = f;   // only waves 0,1 hold nonzero (t<128)
    __syncthreads();
    const float inv = 1.0f / fmaxf(sh[0] + sh[1], 1.0f);
    const float* acct7 = ws + 4096 + (size_t)7 * 4096;
    const int e = t;   // 256 threads = 256 e
    #pragma unroll
    for (int b = 0; b < B; ++b)
        out[b * D + e] = acct7[(size_t)e * B + b] * inv;
}

extern "C" void kernel_launch(void* const* d_in, const int* in_sizes, int n_in,
                              void* d_out, int out_size, void* d_ws, size_t ws_size,
                              hipStream_t stream)
{
    const float* X     = (const float*)d_in[0];
    const float* W     = (const float*)d_in[1];
    const float* bias  = (const float*)d_in[2];
    const float* S     = (const float*)d_in[3];
    const float* rho   = (const float*)d_in[4];
    const float* boost = (const float*)d_in[5];
    const int*   tb    = (const int*)d_in[6];
    float* out = (float*)d_out;
    float* ws  = (float*)d_ws;

    zero_kernel<<<dim3((WS_TOTAL + 511) / 512), dim3(512), 0, stream>>>(ws);
    transpose_kernel<<<dim3(1), dim3(256), 0, stream>>>(X, ws);
    for (int l = 0; l < L; ++l) {
        layer_kernel<<<dim3(N * 4), dim3(512), 0, stream>>>(
            W, bias, S, rho, boost, tb, ws, l);
    }
    finalize_kernel<<<dim3(1), dim3(256), 0, stream>>>(ws, out);
}

// Round 4
// 519.189 us; speedup vs baseline: 1.1176x; 1.1176x over previous
//
#include <hip/hip_runtime.h>
#include <math.h>

#define D 256
#define B 16
#define L 8
#define N 128

static constexpr float LAMBDA_ASYNC = 0.08f;
static constexpr float LAMBDA_TAU   = 0.12f;

// ws layout (floats):
//   xt[256*16]        @ 0      (X transposed, [d][b])
//   acct[8][256*16]   @ 4096   (raw per-layer sums Sigma_fired tanh, [e][b])
//   fired[8][128]     @ 36864
#define WS_TOTAL 37888

__global__ __launch_bounds__(512) void zero_kernel(float* __restrict__ ws) {
    const int i = blockIdx.x * 512 + threadIdx.x;
    if (i < WS_TOTAL) ws[i] = 0.0f;
}

__global__ __launch_bounds__(256) void transpose_kernel(
    const float* __restrict__ X, float* __restrict__ xt) {
    const int d = threadIdx.x;
    #pragma unroll
    for (int b = 0; b < B; ++b) xt[d * B + b] = X[b * D + d];
}

// Grid: 512 blocks = node*4 + e-quarter. Block: 512 threads = 8 waves.
// Wave w: d-rows [w*32, w*32+32). Lane = e within the 64-e quarter.
// Inner loop per row: 1 coalesced W dword + 1 s_load_dwordx16 (vin row) + 16 FMA.
__global__ __launch_bounds__(512, 4) void layer_kernel(
    const float* __restrict__ Wl,         // N*D*D  (this layer)
    const float* __restrict__ biasl,      // N*D
    const float* __restrict__ Sl,         // N*D
    const float* __restrict__ rhol,       // N
    const float* __restrict__ boostl,     // N
    const int*  __restrict__ tb,
    const float* __restrict__ vin,        // [d][b] raw (unscaled), 4096
    const float* __restrict__ fired_prev, // N (null when is_first)
    float* __restrict__ acc_dst,          // [e][b] 4096, atomic +=
    float* __restrict__ fired_cur,        // N
    float depth, int is_first)
{
    __shared__ float red[8 * 64 * 17];   // [wave][e_local][b] padded, 34.8 KB
    __shared__ float sh[16];

    const int t  = threadIdx.x;
    const int n  = blockIdx.x >> 2;
    const int e0 = (blockIdx.x & 3) * 64;

    // ---- preamble: rawdot = <colsum(vin_raw), S_n>, cnt_prev
    float part = 0.0f, cnt_part = 0.0f;
    if (t < 256) {
        const float4 a0 = *(const float4*)&vin[t * 16 + 0];
        const float4 a1 = *(const float4*)&vin[t * 16 + 4];
        const float4 a2 = *(const float4*)&vin[t * 16 + 8];
        const float4 a3 = *(const float4*)&vin[t * 16 + 12];
        const float cs = a0.x + a0.y + a0.z + a0.w + a1.x + a1.y + a1.z + a1.w
                       + a2.x + a2.y + a2.z + a2.w + a3.x + a3.y + a3.z + a3.w;
        part = cs * Sl[n * D + t];
    } else if (!is_first && t < 384) {        // waves 4,5: 128 fired flags
        cnt_part = fired_prev[t - 256];
    }
    #pragma unroll
    for (int o = 32; o > 0; o >>= 1) {
        part     += __shfl_down(part, o);
        cnt_part += __shfl_down(cnt_part, o);
    }
    if ((t & 63) == 0) { sh[t >> 6] = part; sh[8 + (t >> 6)] = cnt_part; }
    __syncthreads();

    float scale;
    bool has_input;
    if (is_first) { scale = 1.0f; has_input = true; }
    else {
        const float cnt_raw = sh[12] + sh[13];
        has_input = (cnt_raw > 0.0f);
        scale = expf(-LAMBDA_ASYNC) / fmaxf(cnt_raw, 1.0f);
    }
    {
        const float rawdot = sh[0] + sh[1] + sh[2] + sh[3];
        const float sdot = scale * rawdot * (1.0f / 16.0f);
        const float tau  = 0.5f * expf(LAMBDA_TAU * (depth - (float)tb[0]));
        const bool fired = (rhol[n] + sdot + boostl[n] >= tau) && has_input;
        if (e0 == 0 && t == 0) fired_cur[n] = fired ? 1.0f : 0.0f;
        if (!fired) return;   // block-uniform; ~4% of blocks at late layers
    }

    // ---- main loop
    const int lane = t & 63;
    const int wu   = __builtin_amdgcn_readfirstlane(t >> 6);  // uniform wave id
    const float* wp = Wl + ((size_t)n * D + (size_t)(wu * 32)) * D + (e0 + lane);
    const float* vp = vin + (size_t)(wu * 32) * 16;           // uniform -> SMEM

    float acc[16];
    #pragma unroll
    for (int b = 0; b < 16; ++b) acc[b] = 0.0f;

    #pragma unroll 4
    for (int j = 0; j < 32; ++j) {
        const float wj = wp[(size_t)j * D];       // 256 B per wave-instr
        const float* v = vp + j * 16;             // uniform 64 B row
        acc[ 0] = fmaf(wj, v[ 0], acc[ 0]);
        acc[ 1] = fmaf(wj, v[ 1], acc[ 1]);
        acc[ 2] = fmaf(wj, v[ 2], acc[ 2]);
        acc[ 3] = fmaf(wj, v[ 3], acc[ 3]);
        acc[ 4] = fmaf(wj, v[ 4], acc[ 4]);
        acc[ 5] = fmaf(wj, v[ 5], acc[ 5]);
        acc[ 6] = fmaf(wj, v[ 6], acc[ 6]);
        acc[ 7] = fmaf(wj, v[ 7], acc[ 7]);
        acc[ 8] = fmaf(wj, v[ 8], acc[ 8]);
        acc[ 9] = fmaf(wj, v[ 9], acc[ 9]);
        acc[10] = fmaf(wj, v[10], acc[10]);
        acc[11] = fmaf(wj, v[11], acc[11]);
        acc[12] = fmaf(wj, v[12], acc[12]);
        acc[13] = fmaf(wj, v[13], acc[13]);
        acc[14] = fmaf(wj, v[14], acc[14]);
        acc[15] = fmaf(wj, v[15], acc[15]);
    }

    // ---- cross-wave d-reduce (8 partials per (e,b)) via padded LDS
    {
        float* rr = &red[((t >> 6) * 64 + lane) * 17];
        #pragma unroll
        for (int b = 0; b < 16; ++b) rr[b] = acc[b];
    }
    __syncthreads();

    // ---- epilogue: thread = (e2, bp -> 2 b); tanh(scale*s + bias), atomic
    {
        const int e2 = t & 63;
        const int bp = t >> 6;
        const float bv = biasl[n * D + e0 + e2];
        #pragma unroll
        for (int q = 0; q < 2; ++q) {
            const int b = bp * 2 + q;
            float s = 0.0f;
            #pragma unroll
            for (int w2 = 0; w2 < 8; ++w2)
                s += red[(w2 * 64 + e2) * 17 + b];
            const float val = tanhf(fmaf(scale, s, bv));
            atomicAdd(&acc_dst[(size_t)(e0 + e2) * 16 + b], val);
        }
    }
}

// out[b][e] = acct7[e][b] / max(cnt7, 1)
__global__ __launch_bounds__(256) void finalize_kernel(
    const float* __restrict__ acct7, const float* __restrict__ fired7,
    float* __restrict__ out)
{
    __shared__ float sh[2];
    const int t = threadIdx.x;
    float f = (t < N) ? fired7[t] : 0.0f;
    #pragma unroll
    for (int o = 32; o > 0; o >>= 1) f += __shfl_down(f, o);
    if ((t & 63) == 0) sh[t >> 6] = f;
    __syncthreads();
    const float inv = 1.0f / fmaxf(sh[0] + sh[1], 1.0f);
    const int e = t;
    #pragma unroll
    for (int b = 0; b < B; ++b)
        out[b * D + e] = acct7[(size_t)e * 16 + b] * inv;
}

extern "C" void kernel_launch(void* const* d_in, const int* in_sizes, int n_in,
                              void* d_out, int out_size, void* d_ws, size_t ws_size,
                              hipStream_t stream)
{
    const float* X     = (const float*)d_in[0];
    const float* W     = (const float*)d_in[1];
    const float* bias  = (const float*)d_in[2];
    const float* S     = (const float*)d_in[3];
    const float* rho   = (const float*)d_in[4];
    const float* boost = (const float*)d_in[5];
    const int*   tb    = (const int*)d_in[6];
    float* out = (float*)d_out;
    float* ws  = (float*)d_ws;

    float* xt    = ws;
    float* acct  = ws + 4096;
    float* fired = ws + 36864;

    zero_kernel<<<dim3((WS_TOTAL + 511) / 512), dim3(512), 0, stream>>>(ws);
    transpose_kernel<<<dim3(1), dim3(256), 0, stream>>>(X, xt);

    for (int l = 0; l < L; ++l) {
        layer_kernel<<<dim3(N * 4), dim3(512), 0, stream>>>(
            W + (size_t)l * N * D * D,
            bias + (size_t)l * N * D,
            S + (size_t)l * N * D,
            rho + (size_t)l * N,
            boost + (size_t)l * N,
            tb,
            (l == 0) ? xt : acct + (size_t)(l - 1) * 4096,
            (l == 0) ? (const float*)nullptr : fired + (size_t)(l - 1) * N,
            acct + (size_t)l * 4096,
            fired + (size_t)l * N,
            (float)(l + 1), (l == 0) ? 1 : 0);
    }

    finalize_kernel<<<dim3(1), dim3(256), 0, stream>>>(
        acct + (size_t)7 * 4096, fired + (size_t)7 * N, out);
}

// Round 5
// 509.146 us; speedup vs baseline: 1.1397x; 1.0197x over previous
//
#include <hip/hip_runtime.h>
#include <math.h>

#define D 256
#define B 16
#define L 8
#define N 128
#define NBLK 256   // 2 blocks per node (e-halves); >=3 blocks/CU capacity -> co-resident
#define NTHR 512

static constexpr float LAMBDA_ASYNC = 0.08f;
static constexpr float LAMBDA_TAU   = 0.12f;

// ws (floats): acct[8][256*16] @0 ([e][b] raw sums), fired[8][128] @32768,
//              barrier counters (uint) @33792 (16 slots)
#define WS_CTR_OFF 33792
#define WS_ZERO_FLOATS (WS_CTR_OFF + 16)

// Block = (node n, e-half h): e in [h*128, h*128+128).
// Main loop: wave w owns d in [w*32, w*32+32); lane -> e-pair (e = e0+lane*2).
// vin[d][b] staged in LDS; rows read as 4 broadcast ds_read_b128 -> 32 FMAs.
__global__ __launch_bounds__(512, 2) void fused_kernel(
    const float* __restrict__ X,      // B*D
    const float* __restrict__ W,      // L*N*D*D
    const float* __restrict__ bias,   // L*N*D
    const float* __restrict__ S,      // L*N*D
    const float* __restrict__ rho,    // L*N
    const float* __restrict__ boost,  // L*N
    const int*  __restrict__ tb,
    float* __restrict__ ws,
    float* __restrict__ out)
{
    __shared__ float vin[D * 16];        // [d][b], 16 KB
    __shared__ float red[4 * 64 * 33];   // 4 slots x 64 lanes x (32+1), 33.8 KB
    __shared__ float sh[16];

    const int t    = threadIdx.x;
    const int w    = t >> 6;
    const int lane = t & 63;
    const int n    = blockIdx.x >> 1;
    const int h    = blockIdx.x & 1;
    const int e0   = h * 128;

    float*    acct  = ws;
    float*    fired = ws + 8 * 4096;
    unsigned* ctr   = (unsigned*)(ws + WS_CTR_OFF);

    const float decay = expf(-LAMBDA_ASYNC);
    const float tbf   = (float)tb[0];

    for (int l = 0; l < L; ++l) {
        // ---- stage vin (raw, unscaled) into LDS as [d][b]
        if (l == 0) {
            if (t < 256) {
                #pragma unroll
                for (int b = 0; b < 16; ++b) vin[t * 16 + b] = X[b * 256 + t];
            }
        } else {
            const float4* src = (const float4*)(acct + (size_t)(l - 1) * 4096);
            ((float4*)vin)[t * 2 + 0] = src[t * 2 + 0];
            ((float4*)vin)[t * 2 + 1] = src[t * 2 + 1];
        }
        __syncthreads();

        // ---- preamble: rawdot (waves 0-3) and prev fired count (waves 4-5)
        float part = 0.0f, cpart = 0.0f;
        if (t < 256) {
            const float4 a0 = *(const float4*)&vin[t * 16 + 0];
            const float4 a1 = *(const float4*)&vin[t * 16 + 4];
            const float4 a2 = *(const float4*)&vin[t * 16 + 8];
            const float4 a3 = *(const float4*)&vin[t * 16 + 12];
            const float cs = a0.x + a0.y + a0.z + a0.w + a1.x + a1.y + a1.z + a1.w
                           + a2.x + a2.y + a2.z + a2.w + a3.x + a3.y + a3.z + a3.w;
            part = cs * S[(size_t)(l * N + n) * D + t];
        } else if (l > 0 && t < 384) {
            cpart = fired[(size_t)(l - 1) * N + (t - 256)];
        }
        #pragma unroll
        for (int o = 32; o > 0; o >>= 1) {
            part  += __shfl_down(part, o);
            cpart += __shfl_down(cpart, o);
        }
        if (lane == 0) { sh[w] = part; sh[8 + w] = cpart; }
        __syncthreads();

        float scale; bool has_input;
        if (l == 0) { scale = 1.0f; has_input = true; }
        else {
            const float cnt_raw = sh[12] + sh[13];
            has_input = (cnt_raw > 0.0f);
            scale = decay / fmaxf(cnt_raw, 1.0f);
        }
        const float rawdot = sh[0] + sh[1] + sh[2] + sh[3];
        const float sdot   = scale * rawdot * (1.0f / 16.0f);
        const float tau    = 0.5f * expf(LAMBDA_TAU * ((float)(l + 1) - tbf));
        const bool fired_n = (rho[l * N + n] + sdot + boost[l * N + n] >= tau) && has_input;
        if (h == 0 && t == 0) fired[(size_t)l * N + n] = fired_n ? 1.0f : 0.0f;

        if (fired_n) {   // block-uniform
            // ---- main loop: 32 d rows for this wave
            const float* wp = W + (size_t)(l * N + n) * D * D + (e0 + lane * 2);
            const int dbase = w * 32;

            float accA[16], accB[16];   // e = e0+lane*2 (+0 / +1)
            #pragma unroll
            for (int b = 0; b < 16; ++b) { accA[b] = 0.0f; accB[b] = 0.0f; }

            #pragma unroll
            for (int j = 0; j < 32; j += 4) {
                float2 wv[4];
                #pragma unroll
                for (int i = 0; i < 4; ++i)
                    wv[i] = *(const float2*)(wp + (size_t)(dbase + j + i) * 256);
                #pragma unroll
                for (int i = 0; i < 4; ++i) {
                    const float* vr = &vin[(dbase + j + i) * 16];
                    const float4 v0 = *(const float4*)(vr + 0);
                    const float4 v1 = *(const float4*)(vr + 4);
                    const float4 v2 = *(const float4*)(vr + 8);
                    const float4 v3 = *(const float4*)(vr + 12);
                    const float wx = wv[i].x, wy = wv[i].y;
                    accA[ 0] = fmaf(wx, v0.x, accA[ 0]); accB[ 0] = fmaf(wy, v0.x, accB[ 0]);
                    accA[ 1] = fmaf(wx, v0.y, accA[ 1]); accB[ 1] = fmaf(wy, v0.y, accB[ 1]);
                    accA[ 2] = fmaf(wx, v0.z, accA[ 2]); accB[ 2] = fmaf(wy, v0.z, accB[ 2]);
                    accA[ 3] = fmaf(wx, v0.w, accA[ 3]); accB[ 3] = fmaf(wy, v0.w, accB[ 3]);
                    accA[ 4] = fmaf(wx, v1.x, accA[ 4]); accB[ 4] = fmaf(wy, v1.x, accB[ 4]);
                    accA[ 5] = fmaf(wx, v1.y, accA[ 5]); accB[ 5] = fmaf(wy, v1.y, accB[ 5]);
                    accA[ 6] = fmaf(wx, v1.z, accA[ 6]); accB[ 6] = fmaf(wy, v1.z, accB[ 6]);
                    accA[ 7] = fmaf(wx, v1.w, accA[ 7]); accB[ 7] = fmaf(wy, v1.w, accB[ 7]);
                    accA[ 8] = fmaf(wx, v2.x, accA[ 8]); accB[ 8] = fmaf(wy, v2.x, accB[ 8]);
                    accA[ 9] = fmaf(wx, v2.y, accA[ 9]); accB[ 9] = fmaf(wy, v2.y, accB[ 9]);
                    accA[10] = fmaf(wx, v2.z, accA[10]); accB[10] = fmaf(wy, v2.z, accB[10]);
                    accA[11] = fmaf(wx, v2.w, accA[11]); accB[11] = fmaf(wy, v2.w, accB[11]);
                    accA[12] = fmaf(wx, v3.x, accA[12]); accB[12] = fmaf(wy, v3.x, accB[12]);
                    accA[13] = fmaf(wx, v3.y, accA[13]); accB[13] = fmaf(wy, v3.y, accB[13]);
                    accA[14] = fmaf(wx, v3.z, accA[14]); accB[14] = fmaf(wy, v3.z, accB[14]);
                    accA[15] = fmaf(wx, v3.w, accA[15]); accB[15] = fmaf(wy, v3.w, accB[15]);
                }
            }

            // ---- cross-wave reduce, 2 rounds into 4 slots (stride 33: conflict-free)
            const int s = w & 3;
            float* rr = &red[(s * 64 + lane) * 33];
            if (w >= 4) {
                #pragma unroll
                for (int b = 0; b < 16; ++b) { rr[b] = accA[b]; rr[16 + b] = accB[b]; }
            }
            __syncthreads();
            if (w < 4) {
                #pragma unroll
                for (int b = 0; b < 16; ++b) { rr[b] += accA[b]; rr[16 + b] += accB[b]; }
            }
            __syncthreads();

            // ---- final: thread t -> 4 cells (e_loc = t>>2, b = (t&3)*4 + q)
            {
                const int e_loc = t >> 2;
                const int b0    = (t & 3) * 4;
                const int lane2 = e_loc >> 1;
                const int sub   = e_loc & 1;
                const float bv  = bias[(size_t)(l * N + n) * D + e0 + e_loc];
                float* dst = acct + (size_t)l * 4096 + (size_t)(e0 + e_loc) * 16;
                #pragma unroll
                for (int q = 0; q < 4; ++q) {
                    const int b = b0 + q;
                    const int o = sub * 16 + b;
                    const float ssum = red[(0 * 64 + lane2) * 33 + o]
                                     + red[(1 * 64 + lane2) * 33 + o]
                                     + red[(2 * 64 + lane2) * 33 + o]
                                     + red[(3 * 64 + lane2) * 33 + o];
                    atomicAdd(&dst[b], tanhf(fmaf(scale, ssum, bv)));
                }
            }
        }

        // ---- grid barrier (all blocks, every layer)
        __threadfence();
        __syncthreads();
        if (t == 0) {
            __hip_atomic_fetch_add(&ctr[l], 1u, __ATOMIC_ACQ_REL, __HIP_MEMORY_SCOPE_AGENT);
            while (__hip_atomic_load(&ctr[l], __ATOMIC_ACQUIRE, __HIP_MEMORY_SCOPE_AGENT)
                   < (unsigned)NBLK) {
                __builtin_amdgcn_s_sleep(2);
            }
        }
        __syncthreads();
    }

    // ---- finalize: block 0 only
    if (blockIdx.x == 0) {
        float f = (t < N) ? fired[(size_t)7 * N + t] : 0.0f;
        #pragma unroll
        for (int o = 32; o > 0; o >>= 1) f += __shfl_down(f, o);
        if (lane == 0) sh[w] = f;
        __syncthreads();
        const float inv = 1.0f / fmaxf(sh[0] + sh[1], 1.0f);
        if (t < 256) {
            const float* a7 = acct + (size_t)7 * 4096 + (size_t)t * 16;
            #pragma unroll
            for (int b = 0; b < 16; ++b) out[b * 256 + t] = a7[b] * inv;
        }
    }
}

extern "C" void kernel_launch(void* const* d_in, const int* in_sizes, int n_in,
                              void* d_out, int out_size, void* d_ws, size_t ws_size,
                              hipStream_t stream)
{
    const float* X     = (const float*)d_in[0];
    const float* W     = (const float*)d_in[1];
    const float* bias  = (const float*)d_in[2];
    const float* S     = (const float*)d_in[3];
    const float* rho   = (const float*)d_in[4];
    const float* boost = (const float*)d_in[5];
    const int*   tb    = (const int*)d_in[6];
    float* out = (float*)d_out;
    float* ws  = (float*)d_ws;

    // zero acct + fired + barrier counters (in-graph, every replay)
    hipMemsetAsync(d_ws, 0, (size_t)WS_ZERO_FLOATS * sizeof(float), stream);

    fused_kernel<<<dim3(NBLK), dim3(NTHR), 0, stream>>>(
        X, W, bias, S, rho, boost, tb, ws, out);
}

// Round 7
// 177.513 us; speedup vs baseline: 3.2688x; 2.8682x over previous
//
#include <hip/hip_runtime.h>
#include <math.h>

#define D 256
#define B 16
#define L 8
#define N 128

static constexpr float LAMBDA_ASYNC = 0.08f;
static constexpr float LAMBDA_TAU   = 0.12f;

// ws layout (floats): xt[4096] @0 ([d][b]), acct[8][4096] @4096 ([e][b] raw
// tanh-sums), fired[8][128] @36864. total 37888.

__global__ __launch_bounds__(512) void zero_kernel(float* __restrict__ p) {
    p[4096 + blockIdx.x * 512 + threadIdx.x] = 0.0f;   // 66 x 512 = 33792
}

__global__ __launch_bounds__(256) void transpose_kernel(
    const float* __restrict__ X, float* __restrict__ xt) {
    const int d = threadIdx.x;
    #pragma unroll
    for (int b = 0; b < B; ++b) xt[d * 16 + b] = X[b * D + d];
}

// Grid: 256 blocks = (node n, e-half h). Block: 512 thr = 8 waves.
// Wave w owns d-rows [w*32, w*32+32); lane owns e = e0 + lane*2 (+0/+1).
// Hot loop per d-row: 1 global_load_dwordx2 of W (512 B/wave, coalesced)
// + 4 broadcast ds_read_b128 (vin row) + 32 FMAs. No fences, no asm.
__global__ __launch_bounds__(512, 2) void layer_kernel(
    const float* __restrict__ Wl,         // N*D*D (this layer)
    const float* __restrict__ biasl,      // N*D
    const float* __restrict__ Sl,         // N*D
    const float* __restrict__ rhol,       // N
    const float* __restrict__ boostl,     // N
    const int*  __restrict__ tb,
    const float* __restrict__ vin_src,    // [d][b] raw (unscaled), 4096 floats
    const float* __restrict__ fired_prev, // N (null for l==0)
    float* __restrict__ acc_dst,          // [e][b] 4096, atomicAdd target
    float* __restrict__ fired_cur,        // N
    float depth, int is_first)
{
    __shared__ float vin[D * 16];        // [d][b], 16 KB
    __shared__ float red[4 * 64 * 33];   // cross-wave partials, 33.8 KB
    __shared__ float sh[16];

    const int t    = threadIdx.x;
    const int w    = t >> 6;
    const int lane = t & 63;
    const int n    = blockIdx.x >> 1;
    const int e0   = (blockIdx.x & 1) * 128;

    // ---- stage vin (raw) into LDS: straight 16 KB vector copy
    {
        const float4* s4 = (const float4*)vin_src;
        ((float4*)vin)[t * 2 + 0] = s4[t * 2 + 0];
        ((float4*)vin)[t * 2 + 1] = s4[t * 2 + 1];
    }
    __syncthreads();

    // ---- preamble: rawdot (waves 0-3), prev fired count (waves 4-5)
    float part = 0.0f, cpart = 0.0f;
    if (t < 256) {
        const float4 a0 = *(const float4*)&vin[t * 16 + 0];
        const float4 a1 = *(const float4*)&vin[t * 16 + 4];
        const float4 a2 = *(const float4*)&vin[t * 16 + 8];
        const float4 a3 = *(const float4*)&vin[t * 16 + 12];
        const float cs = a0.x + a0.y + a0.z + a0.w + a1.x + a1.y + a1.z + a1.w
                       + a2.x + a2.y + a2.z + a2.w + a3.x + a3.y + a3.z + a3.w;
        part = cs * Sl[n * D + t];
    } else if (!is_first && t < 384) {
        cpart = fired_prev[t - 256];
    }
    #pragma unroll
    for (int o = 32; o > 0; o >>= 1) {
        part  += __shfl_down(part, o);
        cpart += __shfl_down(cpart, o);
    }
    if (lane == 0) { sh[w] = part; sh[8 + w] = cpart; }
    __syncthreads();

    float scale; bool has_input;
    if (is_first) { scale = 1.0f; has_input = true; }
    else {
        const float cnt_raw = sh[12] + sh[13];
        has_input = (cnt_raw > 0.0f);
        scale = expf(-LAMBDA_ASYNC) / fmaxf(cnt_raw, 1.0f);
    }
    {
        const float rawdot = sh[0] + sh[1] + sh[2] + sh[3];
        const float sdot = scale * rawdot * (1.0f / 16.0f);
        const float tau  = 0.5f * expf(LAMBDA_TAU * (depth - (float)tb[0]));
        const bool fired = (rhol[n] + sdot + boostl[n] >= tau) && has_input;
        if (e0 == 0 && t == 0) fired_cur[n] = fired ? 1.0f : 0.0f;
        if (!fired) return;   // block-uniform: skip W stream
    }

    // ---- main loop: 32 d-rows for this wave
    const float* wp = Wl + (size_t)n * D * D + (e0 + lane * 2);
    const int dbase = w * 32;

    float accA[16], accB[16];
    #pragma unroll
    for (int b = 0; b < 16; ++b) { accA[b] = 0.0f; accB[b] = 0.0f; }

    #pragma unroll
    for (int j = 0; j < 32; j += 4) {
        float2 wv[4];
        #pragma unroll
        for (int i = 0; i < 4; ++i)
            wv[i] = *(const float2*)(wp + (size_t)(dbase + j + i) * 256);
        #pragma unroll
        for (int i = 0; i < 4; ++i) {
            const float* vr = &vin[(dbase + j + i) * 16];
            const float4 v0 = *(const float4*)(vr + 0);
            const float4 v1 = *(const float4*)(vr + 4);
            const float4 v2 = *(const float4*)(vr + 8);
            const float4 v3 = *(const float4*)(vr + 12);
            const float wx = wv[i].x, wy = wv[i].y;
            accA[ 0] = fmaf(wx, v0.x, accA[ 0]); accB[ 0] = fmaf(wy, v0.x, accB[ 0]);
            accA[ 1] = fmaf(wx, v0.y, accA[ 1]); accB[ 1] = fmaf(wy, v0.y, accB[ 1]);
            accA[ 2] = fmaf(wx, v0.z, accA[ 2]); accB[ 2] = fmaf(wy, v0.z, accB[ 2]);
            accA[ 3] = fmaf(wx, v0.w, accA[ 3]); accB[ 3] = fmaf(wy, v0.w, accB[ 3]);
            accA[ 4] = fmaf(wx, v1.x, accA[ 4]); accB[ 4] = fmaf(wy, v1.x, accB[ 4]);
            accA[ 5] = fmaf(wx, v1.y, accA[ 5]); accB[ 5] = fmaf(wy, v1.y, accB[ 5]);
            accA[ 6] = fmaf(wx, v1.z, accA[ 6]); accB[ 6] = fmaf(wy, v1.z, accB[ 6]);
            accA[ 7] = fmaf(wx, v1.w, accA[ 7]); accB[ 7] = fmaf(wy, v1.w, accB[ 7]);
            accA[ 8] = fmaf(wx, v2.x, accA[ 8]); accB[ 8] = fmaf(wy, v2.x, accB[ 8]);
            accA[ 9] = fmaf(wx, v2.y, accA[ 9]); accB[ 9] = fmaf(wy, v2.y, accB[ 9]);
            accA[10] = fmaf(wx, v2.z, accA[10]); accB[10] = fmaf(wy, v2.z, accB[10]);
            accA[11] = fmaf(wx, v2.w, accA[11]); accB[11] = fmaf(wy, v2.w, accB[11]);
            accA[12] = fmaf(wx, v3.x, accA[12]); accB[12] = fmaf(wy, v3.x, accB[12]);
            accA[13] = fmaf(wx, v3.y, accA[13]); accB[13] = fmaf(wy, v3.y, accB[13]);
            accA[14] = fmaf(wx, v3.z, accA[14]); accB[14] = fmaf(wy, v3.z, accB[14]);
            accA[15] = fmaf(wx, v3.w, accA[15]); accB[15] = fmaf(wy, v3.w, accB[15]);
        }
    }

    // ---- cross-wave reduce: waves 4-7 write slots 0-3, waves 0-3 accumulate
    {
        float* rr = &red[((w & 3) * 64 + lane) * 33];
        if (w >= 4) {
            #pragma unroll
            for (int b = 0; b < 16; ++b) { rr[b] = accA[b]; rr[16 + b] = accB[b]; }
        }
        __syncthreads();
        if (w < 4) {
            #pragma unroll
            for (int b = 0; b < 16; ++b) { rr[b] += accA[b]; rr[16 + b] += accB[b]; }
        }
        __syncthreads();
    }

    // ---- epilogue: thread -> 4 cells; tanh(scale*sum + bias); atomicAdd
    {
        const int e_loc = t >> 2;
        const int b0    = (t & 3) * 4;
        const int lane2 = e_loc >> 1;
        const int sub   = e_loc & 1;
        const float bv  = biasl[n * D + e0 + e_loc];
        float* dst = acc_dst + (size_t)(e0 + e_loc) * 16;
        #pragma unroll
        for (int q = 0; q < 4; ++q) {
            const int b = b0 + q;
            const int o = sub * 16 + b;
            const float ssum = red[(0 * 64 + lane2) * 33 + o]
                             + red[(1 * 64 + lane2) * 33 + o]
                             + red[(2 * 64 + lane2) * 33 + o]
                             + red[(3 * 64 + lane2) * 33 + o];
            atomicAdd(&dst[b], tanhf(fmaf(scale, ssum, bv)));
        }
    }
}

__global__ __launch_bounds__(256) void finalize_kernel(
    const float* __restrict__ acct7, const float* __restrict__ fired7,
    float* __restrict__ out)
{
    __shared__ float sh[2];
    const int t = threadIdx.x;
    float f = (t < N) ? fired7[t] : 0.0f;
    #pragma unroll
    for (int o = 32; o > 0; o >>= 1) f += __shfl_down(f, o);
    if ((t & 63) == 0) sh[t >> 6] = f;
    __syncthreads();
    const float inv = 1.0f / fmaxf(sh[0] + sh[1], 1.0f);
    const int e = t;
    #pragma unroll
    for (int b = 0; b < B; ++b)
        out[b * D + e] = acct7[(size_t)e * 16 + b] * inv;
}

extern "C" void kernel_launch(void* const* d_in, const int* in_sizes, int n_in,
                              void* d_out, int out_size, void* d_ws, size_t ws_size,
                              hipStream_t stream)
{
    const float* X     = (const float*)d_in[0];
    const float* W     = (const float*)d_in[1];
    const float* bias  = (const float*)d_in[2];
    const float* S     = (const float*)d_in[3];
    const float* rho   = (const float*)d_in[4];
    const float* boost = (const float*)d_in[5];
    const int*   tb    = (const int*)d_in[6];
    float* out = (float*)d_out;
    float* ws  = (float*)d_ws;

    float* xt    = ws;
    float* acct  = ws + 4096;
    float* fired = ws + 36864;

    zero_kernel<<<dim3(66), dim3(512), 0, stream>>>(ws);
    transpose_kernel<<<dim3(1), dim3(256), 0, stream>>>(X, xt);

    for (int l = 0; l < L; ++l) {
        layer_kernel<<<dim3(256), dim3(512), 0, stream>>>(
            W + (size_t)l * N * D * D,
            bias + (size_t)l * N * D,
            S + (size_t)l * N * D,
            rho + (size_t)l * N,
            boost + (size_t)l * N,
            tb,
            (l == 0) ? xt : acct + (size_t)(l - 1) * 4096,
            (l == 0) ? (const float*)nullptr : fired + (size_t)(l - 1) * N,
            acct + (size_t)l * 4096,
            fired + (size_t)l * N,
            (float)(l + 1), (l == 0) ? 1 : 0);
    }

    finalize_kernel<<<dim3(1), dim3(256), 0, stream>>>(
        acct + (size_t)7 * 4096, fired + (size_t)7 * N, out);
}

// Round 8
// 134.691 us; speedup vs baseline: 4.3081x; 1.3179x over previous
//
#include <hip/hip_runtime.h>
#include <math.h>

#define D 256
#define B 16
#define L 8
#define N 128

static constexpr float LAMBDA_ASYNC = 0.08f;
static constexpr float LAMBDA_TAU   = 0.12f;

// ws layout (floats):
//   xt[4096]      @ 0       (X transposed, [d][b])
//   acct[8][4096] @ 4096    ([e][b] raw sums  Sigma_fired tanh, per layer)
//   fired[8][128] @ 36864
//   slab[128][4096] @ 37888 (per-node tanh tiles, 2 MB)
// No zeroing needed: fired/acct/slab(used entries) fully rewritten each call.

__global__ __launch_bounds__(256) void transpose_kernel(
    const float* __restrict__ X, float* __restrict__ xt) {
    const int d = threadIdx.x;
    #pragma unroll
    for (int b = 0; b < B; ++b) xt[d * 16 + b] = X[b * D + d];
}

// Grid: 256 blocks = (node n, e-half h). Block: 512 thr = 8 waves.
// Wave w owns d-rows [w*32, w*32+32); lane owns e = e0 + lane*2 (+0/+1).
// Hot loop per d-row: 1 global_load_dwordx2 of W (512 B/wave) + 4 broadcast
// ds_read_b128 (vin row) + 32 FMAs. Epilogue: PLAIN float4 stores to slab
// (no atomics anywhere).
__global__ __launch_bounds__(512, 2) void layer_kernel(
    const float* __restrict__ Wl,         // N*D*D (this layer)
    const float* __restrict__ biasl,      // N*D
    const float* __restrict__ Sl,         // N*D
    const float* __restrict__ rhol,       // N
    const float* __restrict__ boostl,     // N
    const int*  __restrict__ tb,
    const float* __restrict__ vin_src,    // [d][b] raw (unscaled), 4096 floats
    const float* __restrict__ fired_prev, // N (null for l==0)
    float* __restrict__ slab,             // [n][4096] tanh tiles
    float* __restrict__ fired_cur,        // N
    float depth, int is_first)
{
    __shared__ float vin[D * 16];        // [d][b], 16 KB
    __shared__ float red[4 * 64 * 33];   // cross-wave partials, 33.8 KB
    __shared__ float sh[16];

    const int t    = threadIdx.x;
    const int w    = t >> 6;
    const int lane = t & 63;
    const int n    = blockIdx.x >> 1;
    const int e0   = (blockIdx.x & 1) * 128;

    // ---- stage vin (raw) into LDS: straight 16 KB vector copy
    {
        const float4* s4 = (const float4*)vin_src;
        ((float4*)vin)[t * 2 + 0] = s4[t * 2 + 0];
        ((float4*)vin)[t * 2 + 1] = s4[t * 2 + 1];
    }
    __syncthreads();

    // ---- preamble: rawdot (waves 0-3), prev fired count (waves 4-5)
    float part = 0.0f, cpart = 0.0f;
    if (t < 256) {
        const float4 a0 = *(const float4*)&vin[t * 16 + 0];
        const float4 a1 = *(const float4*)&vin[t * 16 + 4];
        const float4 a2 = *(const float4*)&vin[t * 16 + 8];
        const float4 a3 = *(const float4*)&vin[t * 16 + 12];
        const float cs = a0.x + a0.y + a0.z + a0.w + a1.x + a1.y + a1.z + a1.w
                       + a2.x + a2.y + a2.z + a2.w + a3.x + a3.y + a3.z + a3.w;
        part = cs * Sl[n * D + t];
    } else if (!is_first && t < 384) {
        cpart = fired_prev[t - 256];
    }
    #pragma unroll
    for (int o = 32; o > 0; o >>= 1) {
        part  += __shfl_down(part, o);
        cpart += __shfl_down(cpart, o);
    }
    if (lane == 0) { sh[w] = part; sh[8 + w] = cpart; }
    __syncthreads();

    float scale; bool has_input;
    if (is_first) { scale = 1.0f; has_input = true; }
    else {
        const float cnt_raw = sh[12] + sh[13];
        has_input = (cnt_raw > 0.0f);
        scale = expf(-LAMBDA_ASYNC) / fmaxf(cnt_raw, 1.0f);
    }
    {
        const float rawdot = sh[0] + sh[1] + sh[2] + sh[3];
        const float sdot = scale * rawdot * (1.0f / 16.0f);
        const float tau  = 0.5f * expf(LAMBDA_TAU * (depth - (float)tb[0]));
        const bool fired = (rhol[n] + sdot + boostl[n] >= tau) && has_input;
        if (e0 == 0 && t == 0) fired_cur[n] = fired ? 1.0f : 0.0f;
        if (!fired) return;   // block-uniform: skip W stream + slab write
    }

    // ---- main loop: 32 d-rows for this wave
    const float* wp = Wl + (size_t)n * D * D + (e0 + lane * 2);
    const int dbase = w * 32;

    float accA[16], accB[16];
    #pragma unroll
    for (int b = 0; b < 16; ++b) { accA[b] = 0.0f; accB[b] = 0.0f; }

    #pragma unroll
    for (int j = 0; j < 32; j += 4) {
        float2 wv[4];
        #pragma unroll
        for (int i = 0; i < 4; ++i)
            wv[i] = *(const float2*)(wp + (size_t)(dbase + j + i) * 256);
        #pragma unroll
        for (int i = 0; i < 4; ++i) {
            const float* vr = &vin[(dbase + j + i) * 16];
            const float4 v0 = *(const float4*)(vr + 0);
            const float4 v1 = *(const float4*)(vr + 4);
            const float4 v2 = *(const float4*)(vr + 8);
            const float4 v3 = *(const float4*)(vr + 12);
            const float wx = wv[i].x, wy = wv[i].y;
            accA[ 0] = fmaf(wx, v0.x, accA[ 0]); accB[ 0] = fmaf(wy, v0.x, accB[ 0]);
            accA[ 1] = fmaf(wx, v0.y, accA[ 1]); accB[ 1] = fmaf(wy, v0.y, accB[ 1]);
            accA[ 2] = fmaf(wx, v0.z, accA[ 2]); accB[ 2] = fmaf(wy, v0.z, accB[ 2]);
            accA[ 3] = fmaf(wx, v0.w, accA[ 3]); accB[ 3] = fmaf(wy, v0.w, accB[ 3]);
            accA[ 4] = fmaf(wx, v1.x, accA[ 4]); accB[ 4] = fmaf(wy, v1.x, accB[ 4]);
            accA[ 5] = fmaf(wx, v1.y, accA[ 5]); accB[ 5] = fmaf(wy, v1.y, accB[ 5]);
            accA[ 6] = fmaf(wx, v1.z, accA[ 6]); accB[ 6] = fmaf(wy, v1.z, accB[ 6]);
            accA[ 7] = fmaf(wx, v1.w, accA[ 7]); accB[ 7] = fmaf(wy, v1.w, accB[ 7]);
            accA[ 8] = fmaf(wx, v2.x, accA[ 8]); accB[ 8] = fmaf(wy, v2.x, accB[ 8]);
            accA[ 9] = fmaf(wx, v2.y, accA[ 9]); accB[ 9] = fmaf(wy, v2.y, accB[ 9]);
            accA[10] = fmaf(wx, v2.z, accA[10]); accB[10] = fmaf(wy, v2.z, accB[10]);
            accA[11] = fmaf(wx, v2.w, accA[11]); accB[11] = fmaf(wy, v2.w, accB[11]);
            accA[12] = fmaf(wx, v3.x, accA[12]); accB[12] = fmaf(wy, v3.x, accB[12]);
            accA[13] = fmaf(wx, v3.y, accA[13]); accB[13] = fmaf(wy, v3.y, accB[13]);
            accA[14] = fmaf(wx, v3.z, accA[14]); accB[14] = fmaf(wy, v3.z, accB[14]);
            accA[15] = fmaf(wx, v3.w, accA[15]); accB[15] = fmaf(wy, v3.w, accB[15]);
        }
    }

    // ---- cross-wave reduce: waves 4-7 write slots 0-3, waves 0-3 accumulate
    {
        float* rr = &red[((w & 3) * 64 + lane) * 33];
        if (w >= 4) {
            #pragma unroll
            for (int b = 0; b < 16; ++b) { rr[b] = accA[b]; rr[16 + b] = accB[b]; }
        }
        __syncthreads();
        if (w < 4) {
            #pragma unroll
            for (int b = 0; b < 16; ++b) { rr[b] += accA[b]; rr[16 + b] += accB[b]; }
        }
        __syncthreads();
    }

    // ---- epilogue: thread -> 4 cells; tanh(scale*sum + bias); PLAIN store
    {
        const int e_loc = t >> 2;
        const int b0    = (t & 3) * 4;
        const int lane2 = e_loc >> 1;
        const int sub   = e_loc & 1;
        const float bv  = biasl[n * D + e0 + e_loc];
        float* dst = slab + (size_t)n * 4096 + (size_t)(e0 + e_loc) * 16 + b0;
        float4 o4;
        {
            const int o0 = sub * 16 + b0;
            const float s0 = red[(0*64+lane2)*33 + o0+0] + red[(1*64+lane2)*33 + o0+0]
                           + red[(2*64+lane2)*33 + o0+0] + red[(3*64+lane2)*33 + o0+0];
            const float s1 = red[(0*64+lane2)*33 + o0+1] + red[(1*64+lane2)*33 + o0+1]
                           + red[(2*64+lane2)*33 + o0+1] + red[(3*64+lane2)*33 + o0+1];
            const float s2 = red[(0*64+lane2)*33 + o0+2] + red[(1*64+lane2)*33 + o0+2]
                           + red[(2*64+lane2)*33 + o0+2] + red[(3*64+lane2)*33 + o0+2];
            const float s3 = red[(0*64+lane2)*33 + o0+3] + red[(1*64+lane2)*33 + o0+3]
                           + red[(2*64+lane2)*33 + o0+3] + red[(3*64+lane2)*33 + o0+3];
            o4.x = tanhf(fmaf(scale, s0, bv));
            o4.y = tanhf(fmaf(scale, s1, bv));
            o4.z = tanhf(fmaf(scale, s2, bv));
            o4.w = tanhf(fmaf(scale, s3, bv));
        }
        *(float4*)dst = o4;
    }
}

// acct[c] = sum_n fired[n] * slab[n][c]   (branchless; stale slabs x 0 = 0)
__global__ __launch_bounds__(512) void reduce_kernel(
    const float* __restrict__ slab, const float* __restrict__ fired_l,
    float* __restrict__ acct_l)
{
    const int c = blockIdx.x * 512 + threadIdx.x;   // 8 blocks x 512 = 4096
    float s0 = 0.f, s1 = 0.f, s2 = 0.f, s3 = 0.f;
    #pragma unroll 4
    for (int n = 0; n < 128; n += 4) {
        s0 = fmaf(fired_l[n + 0], slab[(size_t)(n + 0) * 4096 + c], s0);
        s1 = fmaf(fired_l[n + 1], slab[(size_t)(n + 1) * 4096 + c], s1);
        s2 = fmaf(fired_l[n + 2], slab[(size_t)(n + 2) * 4096 + c], s2);
        s3 = fmaf(fired_l[n + 3], slab[(size_t)(n + 3) * 4096 + c], s3);
    }
    acct_l[c] = (s0 + s1) + (s2 + s3);
}

__global__ __launch_bounds__(256) void finalize_kernel(
    const float* __restrict__ acct7, const float* __restrict__ fired7,
    float* __restrict__ out)
{
    __shared__ float sh[2];
    const int t = threadIdx.x;
    float f = (t < N) ? fired7[t] : 0.0f;
    #pragma unroll
    for (int o = 32; o > 0; o >>= 1) f += __shfl_down(f, o);
    if ((t & 63) == 0) sh[t >> 6] = f;
    __syncthreads();
    const float inv = 1.0f / fmaxf(sh[0] + sh[1], 1.0f);
    const int e = t;
    #pragma unroll
    for (int b = 0; b < B; ++b)
        out[b * D + e] = acct7[(size_t)e * 16 + b] * inv;
}

extern "C" void kernel_launch(void* const* d_in, const int* in_sizes, int n_in,
                              void* d_out, int out_size, void* d_ws, size_t ws_size,
                              hipStream_t stream)
{
    const float* X     = (const float*)d_in[0];
    const float* W     = (const float*)d_in[1];
    const float* bias  = (const float*)d_in[2];
    const float* S     = (const float*)d_in[3];
    const float* rho   = (const float*)d_in[4];
    const float* boost = (const float*)d_in[5];
    const int*   tb    = (const int*)d_in[6];
    float* out = (float*)d_out;
    float* ws  = (float*)d_ws;

    float* xt    = ws;
    float* acct  = ws + 4096;
    float* fired = ws + 36864;
    float* slab  = ws + 37888;

    transpose_kernel<<<dim3(1), dim3(256), 0, stream>>>(X, xt);

    for (int l = 0; l < L; ++l) {
        layer_kernel<<<dim3(256), dim3(512), 0, stream>>>(
            W + (size_t)l * N * D * D,
            bias + (size_t)l * N * D,
            S + (size_t)l * N * D,
            rho + (size_t)l * N,
            boost + (size_t)l * N,
            tb,
            (l == 0) ? xt : acct + (size_t)(l - 1) * 4096,
            (l == 0) ? (const float*)nullptr : fired + (size_t)(l - 1) * N,
            slab,
            fired + (size_t)l * N,
            (float)(l + 1), (l == 0) ? 1 : 0);
        reduce_kernel<<<dim3(8), dim3(512), 0, stream>>>(
            slab, fired + (size_t)l * N, acct + (size_t)l * 4096);
    }

    finalize_kernel<<<dim3(1), dim3(256), 0, stream>>>(
        acct + (size_t)7 * 4096, fired + (size_t)7 * N, out);
}

// Round 9
// 115.913 us; speedup vs baseline: 5.0060x; 1.1620x over previous
//
#include <hip/hip_runtime.h>
#include <math.h>

#define D 256
#define B 16
#define L 8
#define N 128

static constexpr float LAMBDA_ASYNC = 0.08f;
static constexpr float LAMBDA_TAU   = 0.12f;

// ws layout (floats):
//   acct[8][4096] @ 0      (PRE-SCALED vin for next layer, [e][b])
//   meta[16]      @ 32768  (meta[l] = fired count of layer l)
//   fired[8][128] @ 32784
//   slab[128][4096] @ 33808 (per-node tanh tiles, 2 MB)
// No zeroing needed: every consumed entry is rewritten each call
// (stale slab entries are masked by fired=0 in the reduce).

#define OFF_META  32768
#define OFF_FIRED 32784
#define OFF_SLAB  33808

// Grid: 256 blocks = (node n, e-half h). Block: 512 thr = 8 waves.
// Wave w owns d-rows [w*32, w*32+32); lane owns e = e0 + lane*2 (+0/+1).
// Hot loop per d-row: 1 global_load_dwordx2 of W (512 B/wave) + 4 broadcast
// ds_read_b128 (vin row) + 32 FMAs. Plain float4 stores to slab. No atomics.
__global__ __launch_bounds__(512, 2) void layer_kernel(
    const float* __restrict__ Wl,         // N*D*D (this layer)
    const float* __restrict__ biasl,      // N*D
    const float* __restrict__ Sl,         // N*D
    const float* __restrict__ rhol,       // N
    const float* __restrict__ boostl,     // N
    const int*  __restrict__ tb,
    const float* __restrict__ vin_src,    // acct[l-1]: pre-scaled [d][b] (null if l==0)
    const float* __restrict__ X,          // B*D (used if l==0)
    const float* __restrict__ meta_prev,  // meta[l-1] (null if l==0)
    float* __restrict__ slab,             // [n][4096] tanh tiles
    float* __restrict__ fired_cur,        // N
    float depth, int is_first)
{
    __shared__ float vin[D * 16];        // [d][b], 16 KB
    __shared__ float red[4 * 64 * 33];   // cross-wave partials, 33.8 KB
    __shared__ float sh[8];

    const int t    = threadIdx.x;
    const int w    = t >> 6;
    const int lane = t & 63;
    const int n    = blockIdx.x >> 1;
    const int e0   = (blockIdx.x & 1) * 128;

    // ---- stage vin into LDS as [d][b] (pre-scaled for l>0; X transposed for l==0)
    if (is_first) {
        #pragma unroll
        for (int k = 0; k < 2; ++k) {
            const float4 xv = ((const float4*)X)[t * 2 + k];
            const int idx = (t * 2 + k) * 4;          // = b*256 + d0
            const int b   = idx >> 8;
            const int d0  = idx & 255;
            vin[(d0 + 0) * 16 + b] = xv.x;
            vin[(d0 + 1) * 16 + b] = xv.y;
            vin[(d0 + 2) * 16 + b] = xv.z;
            vin[(d0 + 3) * 16 + b] = xv.w;
        }
    } else {
        const float4* s4 = (const float4*)vin_src;
        ((float4*)vin)[t * 2 + 0] = s4[t * 2 + 0];
        ((float4*)vin)[t * 2 + 1] = s4[t * 2 + 1];
    }
    __syncthreads();

    // ---- preamble: rawdot = <colsum(vin), S_n>  (vin already scaled)
    float part = 0.0f;
    if (t < 256) {
        const float4 a0 = *(const float4*)&vin[t * 16 + 0];
        const float4 a1 = *(const float4*)&vin[t * 16 + 4];
        const float4 a2 = *(const float4*)&vin[t * 16 + 8];
        const float4 a3 = *(const float4*)&vin[t * 16 + 12];
        const float cs = a0.x + a0.y + a0.z + a0.w + a1.x + a1.y + a1.z + a1.w
                       + a2.x + a2.y + a2.z + a2.w + a3.x + a3.y + a3.z + a3.w;
        part = cs * Sl[n * D + t];
    }
    #pragma unroll
    for (int o = 32; o > 0; o >>= 1) part += __shfl_down(part, o);
    if (lane == 0) sh[w] = part;
    __syncthreads();

    {
        const bool has_input = is_first ? true : (meta_prev[0] > 0.0f);
        const float sdot = (sh[0] + sh[1] + sh[2] + sh[3]) * (1.0f / 16.0f);
        const float tau  = 0.5f * expf(LAMBDA_TAU * (depth - (float)tb[0]));
        const bool fired = (rhol[n] + sdot + boostl[n] >= tau) && has_input;
        if (e0 == 0 && t == 0) fired_cur[n] = fired ? 1.0f : 0.0f;
        if (!fired) return;   // block-uniform: skip W stream + slab write
    }

    // ---- main loop: 32 d-rows for this wave
    const float* wp = Wl + (size_t)n * D * D + (e0 + lane * 2);
    const int dbase = w * 32;

    float accA[16], accB[16];
    #pragma unroll
    for (int b = 0; b < 16; ++b) { accA[b] = 0.0f; accB[b] = 0.0f; }

    #pragma unroll
    for (int j = 0; j < 32; j += 4) {
        float2 wv[4];
        #pragma unroll
        for (int i = 0; i < 4; ++i)
            wv[i] = *(const float2*)(wp + (size_t)(dbase + j + i) * 256);
        #pragma unroll
        for (int i = 0; i < 4; ++i) {
            const float* vr = &vin[(dbase + j + i) * 16];
            const float4 v0 = *(const float4*)(vr + 0);
            const float4 v1 = *(const float4*)(vr + 4);
            const float4 v2 = *(const float4*)(vr + 8);
            const float4 v3 = *(const float4*)(vr + 12);
            const float wx = wv[i].x, wy = wv[i].y;
            accA[ 0] = fmaf(wx, v0.x, accA[ 0]); accB[ 0] = fmaf(wy, v0.x, accB[ 0]);
            accA[ 1] = fmaf(wx, v0.y, accA[ 1]); accB[ 1] = fmaf(wy, v0.y, accB[ 1]);
            accA[ 2] = fmaf(wx, v0.z, accA[ 2]); accB[ 2] = fmaf(wy, v0.z, accB[ 2]);
            accA[ 3] = fmaf(wx, v0.w, accA[ 3]); accB[ 3] = fmaf(wy, v0.w, accB[ 3]);
            accA[ 4] = fmaf(wx, v1.x, accA[ 4]); accB[ 4] = fmaf(wy, v1.x, accB[ 4]);
            accA[ 5] = fmaf(wx, v1.y, accA[ 5]); accB[ 5] = fmaf(wy, v1.y, accB[ 5]);
            accA[ 6] = fmaf(wx, v1.z, accA[ 6]); accB[ 6] = fmaf(wy, v1.z, accB[ 6]);
            accA[ 7] = fmaf(wx, v1.w, accA[ 7]); accB[ 7] = fmaf(wy, v1.w, accB[ 7]);
            accA[ 8] = fmaf(wx, v2.x, accA[ 8]); accB[ 8] = fmaf(wy, v2.x, accB[ 8]);
            accA[ 9] = fmaf(wx, v2.y, accA[ 9]); accB[ 9] = fmaf(wy, v2.y, accB[ 9]);
            accA[10] = fmaf(wx, v2.z, accA[10]); accB[10] = fmaf(wy, v2.z, accB[10]);
            accA[11] = fmaf(wx, v2.w, accA[11]); accB[11] = fmaf(wy, v2.w, accB[11]);
            accA[12] = fmaf(wx, v3.x, accA[12]); accB[12] = fmaf(wy, v3.x, accB[12]);
            accA[13] = fmaf(wx, v3.y, accA[13]); accB[13] = fmaf(wy, v3.y, accB[13]);
            accA[14] = fmaf(wx, v3.z, accA[14]); accB[14] = fmaf(wy, v3.z, accB[14]);
            accA[15] = fmaf(wx, v3.w, accA[15]); accB[15] = fmaf(wy, v3.w, accB[15]);
        }
    }

    // ---- cross-wave reduce: waves 4-7 write slots 0-3, waves 0-3 accumulate
    {
        float* rr = &red[((w & 3) * 64 + lane) * 33];
        if (w >= 4) {
            #pragma unroll
            for (int b = 0; b < 16; ++b) { rr[b] = accA[b]; rr[16 + b] = accB[b]; }
        }
        __syncthreads();
        if (w < 4) {
            #pragma unroll
            for (int b = 0; b < 16; ++b) { rr[b] += accA[b]; rr[16 + b] += accB[b]; }
        }
        __syncthreads();
    }

    // ---- epilogue: thread -> 4 cells; tanh(sum + bias); plain float4 store
    {
        const int e_loc = t >> 2;
        const int b0    = (t & 3) * 4;
        const int lane2 = e_loc >> 1;
        const int sub   = e_loc & 1;
        const float bv  = biasl[n * D + e0 + e_loc];
        float* dst = slab + (size_t)n * 4096 + (size_t)(e0 + e_loc) * 16 + b0;
        const int o0 = sub * 16 + b0;
        float4 o4;
        o4.x = tanhf(red[(0*64+lane2)*33 + o0+0] + red[(1*64+lane2)*33 + o0+0]
                   + red[(2*64+lane2)*33 + o0+0] + red[(3*64+lane2)*33 + o0+0] + bv);
        o4.y = tanhf(red[(0*64+lane2)*33 + o0+1] + red[(1*64+lane2)*33 + o0+1]
                   + red[(2*64+lane2)*33 + o0+1] + red[(3*64+lane2)*33 + o0+1] + bv);
        o4.z = tanhf(red[(0*64+lane2)*33 + o0+2] + red[(1*64+lane2)*33 + o0+2]
                   + red[(2*64+lane2)*33 + o0+2] + red[(3*64+lane2)*33 + o0+2] + bv);
        o4.w = tanhf(red[(0*64+lane2)*33 + o0+3] + red[(1*64+lane2)*33 + o0+3]
                   + red[(2*64+lane2)*33 + o0+3] + red[(3*64+lane2)*33 + o0+3] + bv);
        *(float4*)dst = o4;
    }
}

// 64 blocks x 256 thr. Block covers 64 cells; thread = (cell, n-chunk of 32).
// acct[c] = (decay/max(cnt,1)) * sum_n fired[n]*slab[n][c];  meta = cnt.
__global__ __launch_bounds__(256) void reduce_mid(
    const float* __restrict__ slab, const float* __restrict__ fired_l,
    float* __restrict__ acct_l, float* __restrict__ meta_l)
{
    __shared__ float part[256];
    __shared__ float shcnt;
    const int t    = threadIdx.x;
    const int cell = blockIdx.x * 64 + (t & 63);
    const int n0   = (t >> 6) * 32;

    float s = 0.0f;
    #pragma unroll 8
    for (int k = 0; k < 32; ++k)
        s = fmaf(fired_l[n0 + k], slab[(size_t)(n0 + k) * 4096 + cell], s);
    part[t] = s;

    if (t < 64) {             // wave 0: fired count
        float c = fired_l[t] + fired_l[t + 64];
        #pragma unroll
        for (int o = 32; o > 0; o >>= 1) c += __shfl_down(c, o);
        if (t == 0) shcnt = c;
    }
    __syncthreads();

    if (t < 64) {
        const float cnt   = shcnt;
        const float scale = expf(-LAMBDA_ASYNC) / fmaxf(cnt, 1.0f);
        const float v = part[t] + part[64 + t] + part[128 + t] + part[192 + t];
        acct_l[blockIdx.x * 64 + t] = v * scale;
        if (blockIdx.x == 0 && t == 0) meta_l[0] = cnt;
    }
}

// Final: out[b][e] = sum_n fired7[n]*slab[n][e*16+b] / max(cnt,1)
__global__ __launch_bounds__(256) void reduce_final(
    const float* __restrict__ slab, const float* __restrict__ fired_l,
    float* __restrict__ out)
{
    __shared__ float part[256];
    __shared__ float shcnt;
    const int t    = threadIdx.x;
    const int cell = blockIdx.x * 64 + (t & 63);
    const int n0   = (t >> 6) * 32;

    float s = 0.0f;
    #pragma unroll 8
    for (int k = 0; k < 32; ++k)
        s = fmaf(fired_l[n0 + k], slab[(size_t)(n0 + k) * 4096 + cell], s);
    part[t] = s;

    if (t < 64) {
        float c = fired_l[t] + fired_l[t + 64];
        #pragma unroll
        for (int o = 32; o > 0; o >>= 1) c += __shfl_down(c, o);
        if (t == 0) shcnt = c;
    }
    __syncthreads();

    if (t < 64) {
        const float inv = 1.0f / fmaxf(shcnt, 1.0f);
        const int c = blockIdx.x * 64 + t;
        const float v = (part[t] + part[64 + t] + part[128 + t] + part[192 + t]) * inv;
        const int e = c >> 4, b = c & 15;
        out[b * 256 + e] = v;
    }
}

extern "C" void kernel_launch(void* const* d_in, const int* in_sizes, int n_in,
                              void* d_out, int out_size, void* d_ws, size_t ws_size,
                              hipStream_t stream)
{
    const float* X     = (const float*)d_in[0];
    const float* W     = (const float*)d_in[1];
    const float* bias  = (const float*)d_in[2];
    const float* S     = (const float*)d_in[3];
    const float* rho   = (const float*)d_in[4];
    const float* boost = (const float*)d_in[5];
    const int*   tb    = (const int*)d_in[6];
    float* out = (float*)d_out;
    float* ws  = (float*)d_ws;

    float* acct  = ws;
    float* meta  = ws + OFF_META;
    float* fired = ws + OFF_FIRED;
    float* slab  = ws + OFF_SLAB;

    for (int l = 0; l < L; ++l) {
        layer_kernel<<<dim3(256), dim3(512), 0, stream>>>(
            W + (size_t)l * N * D * D,
            bias + (size_t)l * N * D,
            S + (size_t)l * N * D,
            rho + (size_t)l * N,
            boost + (size_t)l * N,
            tb,
            (l == 0) ? (const float*)nullptr : acct + (size_t)(l - 1) * 4096,
            X,
            (l == 0) ? (const float*)nullptr : meta + (l - 1),
            slab,
            fired + (size_t)l * N,
            (float)(l + 1), (l == 0) ? 1 : 0);
        if (l < L - 1) {
            reduce_mid<<<dim3(64), dim3(256), 0, stream>>>(
                slab, fired + (size_t)l * N,
                acct + (size_t)l * 4096, meta + l);
        } else {
            reduce_final<<<dim3(64), dim3(256), 0, stream>>>(
                slab, fired + (size_t)l * N, out);
        }
    }
}